// Round 5
// baseline (1006.017 us; speedup 1.0000x reference)
//
#include <hip/hip_runtime.h>
#include <math.h>

#define BB 8
#define CC 256
#define HH 128
#define WW 128
#define NN (HH*WW)          // 16384
#define NBVEC 16
#define CSPLIT 16
#define CCHUNK (CC/CSPLIT)  // 16
#define NBX (NN/256)        // 64

// ---------------- workspace layout (bytes) ----------------
// score  double[B][N]           @ 0        : 1048576
// d2part float [CSPLIT][B][N]   @ 1048576  : 8388608
// wpart  double[NBX][B][C]      @ 9437184  : 1048576
// sumSim double[2][B]           @ 10485760 : 128
// bmaxv  double[B][NBX]         @ 10485888 : 4096
// bmaxi  int   [B][NBX]         @ 10489984 : 2048
// rv     float [B][C]           @ 10492032 : 8192
// ticket int   [NBVEC][B]       @ 10500224 : 512
// total ~10.5 MB

// Fused kernel: ONE x-pass per iteration. Block (nb, cz, b) owns
// c in [cz*16, cz*16+16), n in [nb*256, nb*256+256).
// Prologue is now just two coalesced LDS fills (sel/rv moved to finish's
// last-block; round-4 post-mortem: per-block argmax tree + strided rv
// gather was serial latency repeated over 8 dispatch rounds per CU).
// Staging is float4 (16 B/lane VMEM sweet spot), scalar LDS stores keep
// the 257-stride conflict-free layout. Pass A reads its 16 c's from LDS
// (bit-identical values, same fp64 chain order as round 4).
__global__ __launch_bounds__(256, 8)
void fused_kernel(const float* __restrict__ x,
                  float* __restrict__ out,
                  const float* __restrict__ rv,
                  float* __restrict__ d2part,
                  double* __restrict__ wpart, int iter)
{
    const int b  = blockIdx.z;
    const int cz = blockIdx.y;
    const int nb = blockIdx.x;
    const int t  = threadIdx.x;

    __shared__ float  s_x[CCHUNK][257];   // 257-stride: all accesses <=2-way (free)
    __shared__ float  s_sim[256];
    __shared__ float  s_rv[CCHUNK];
    __shared__ double s_part[16][CCHUNK];

    const float* out_sims = out + (size_t)NBVEC*BB*CC;        // [NBVEC][B][N]

    if (iter < NBVEC && t < CCHUNK)
        s_rv[t] = rv[(size_t)b*CC + (size_t)cz*CCHUNK + t];
    if (iter > 0)
        s_sim[t] = out_sims[(size_t)(iter-1)*BB*NN + (size_t)b*NN + nb*256 + t];

    // ---- cooperative float4 staging: row = t>>4, 16 threads/row, 4 f4 each ----
    const int row = t >> 4;
    const int l16 = t & 15;
    const float* xrow = x + ((size_t)b*CC + (size_t)cz*CCHUNK + row)*NN + (size_t)nb*256;
    float4 v0 = *(const float4*)(xrow + l16*4);
    float4 v1 = *(const float4*)(xrow + l16*4 + 64);
    float4 v2 = *(const float4*)(xrow + l16*4 + 128);
    float4 v3 = *(const float4*)(xrow + l16*4 + 192);
    s_x[row][l16*4+0]       = v0.x; s_x[row][l16*4+1]       = v0.y;
    s_x[row][l16*4+2]       = v0.z; s_x[row][l16*4+3]       = v0.w;
    s_x[row][l16*4+64]      = v1.x; s_x[row][l16*4+65]      = v1.y;
    s_x[row][l16*4+66]      = v1.z; s_x[row][l16*4+67]      = v1.w;
    s_x[row][l16*4+128]     = v2.x; s_x[row][l16*4+129]     = v2.y;
    s_x[row][l16*4+130]     = v2.z; s_x[row][l16*4+131]     = v2.w;
    s_x[row][l16*4+192]     = v3.x; s_x[row][l16*4+193]     = v3.y;
    s_x[row][l16*4+194]     = v3.z; s_x[row][l16*4+195]     = v3.w;
    __syncthreads();

    // ---- pass A: d2 partial (fp64 chain, fixed c-ascending order) ----
    if (iter < NBVEC) {
        double acc = 0.0;
        #pragma unroll
        for (int c = 0; c < CCHUNK; ++c) {
            double diff = (double)s_x[c][t] - (double)s_rv[c];
            acc = fma(diff, diff, acc);
        }
        d2part[((size_t)cz*BB + b)*NN + (size_t)nb*256 + t] = (float)acc;
    }

    // ---- pass B: wsum partial for previous iter's sim ----
    if (iter > 0) {
        const int c = t & 15;        // 16 c's
        const int g = t >> 4;        // 16 n-groups of 16
        double w = 0.0;
        #pragma unroll
        for (int k = 0; k < 16; ++k) {
            const int nn2 = g*16 + k;
            w = fma((double)s_sim[nn2], (double)s_x[c][nn2], w);
        }
        s_part[g][c] = w;
        __syncthreads();
        if (t < CCHUNK) {
            double t0 = 0.0, t1 = 0.0;
            #pragma unroll
            for (int gg = 0; gg < 16; gg += 2) {     // fixed order, 2 chains
                t0 += s_part[gg][t];
                t1 += s_part[gg+1][t];
            }
            wpart[((size_t)nb*BB + b)*CC + (size_t)cz*CCHUNK + t] = t0 + t1;
        }
    }
}

// Finisher: grid (N/256, B).
//  - d2 = sum of 16 fp32 partials; sim = exp(-sqrt(d2+1e-12)/20)
//  - out_sims (fp32), score update (fp64)
//  - sumSim + argmax via per-wave shfl butterflies (semilattice: order-free)
//  - block (0,b), iter>0: repr_{iter-1} finalize
//  - LAST block per b (atomic ticket): final argmax over the 64 partials,
//    rv gather for iter+1, selpos bump  (replaces fused's per-block prologue)
__global__ void finish_kernel(const float* __restrict__ x,
                              float* __restrict__ out,
                              double* __restrict__ score,
                              const float* __restrict__ d2part,
                              double* __restrict__ sumSim,
                              const double* __restrict__ wpart,
                              double* __restrict__ bmaxv,
                              int* __restrict__ bmaxi,
                              float* __restrict__ rv,
                              int* __restrict__ ticket, int iter)
{
    const int b = blockIdx.y;
    const int t = threadIdx.x;
    const int n = blockIdx.x * 256 + t;
    const size_t si = (size_t)b*NN + n;
    const int lane = t & 63;
    const int wave = t >> 6;

    __shared__ double s_ws[4];
    __shared__ double s_wv[4];
    __shared__ int    s_wi[4];
    __shared__ int    s_last;
    __shared__ double s_val[NBX];
    __shared__ int    s_idx[NBX];

    float* out_sims   = out + (size_t)NBVEC*BB*CC;            // [NBVEC][B][N]
    float* out_selpos = out_sims + (size_t)NBVEC*BB*NN;       // [B][N]

    double a0 = 0.0, a1 = 0.0;
    #pragma unroll
    for (int cz = 0; cz < CSPLIT; cz += 2) {
        a0 += (double)d2part[((size_t)cz*BB + b)*NN + n];
        a1 += (double)d2part[((size_t)(cz+1)*BB + b)*NN + n];
    }
    double d2 = a0 + a1;

    double d   = sqrt(d2 + 1e-12);
    double sim = exp(-(d / 20.0));

    out_sims[(size_t)iter*BB*NN + si] = (float)sim;

    double sc;
    if (iter == 0) sc = 1.0 - sim;
    else           sc = (1.0 - sim) * score[si];
    score[si] = sc;

    // per-wave sumSim reduce
    double v = sim;
    #pragma unroll
    for (int off = 32; off > 0; off >>= 1) v += __shfl_down(v, off, 64);

    // per-wave argmax reduce (max, lower-idx-on-tie)
    double bv = sc; int bi = n;
    #pragma unroll
    for (int off = 32; off > 0; off >>= 1) {
        double ov = __shfl_down(bv, off, 64);
        int    oi = __shfl_down(bi, off, 64);
        if (ov > bv || (ov == bv && oi < bi)) { bv = ov; bi = oi; }
    }

    if (lane == 0) { s_ws[wave] = v; s_wv[wave] = bv; s_wi[wave] = bi; }
    __syncthreads();
    if (t == 0) {
        double tot = ((s_ws[0] + s_ws[1]) + (s_ws[2] + s_ws[3]));
        atomicAdd(&sumSim[(size_t)(iter & 1)*BB + b], tot);
        double cv = s_wv[0]; int ci = s_wi[0];
        #pragma unroll
        for (int w = 1; w < 4; ++w) {
            if (s_wv[w] > cv || (s_wv[w] == cv && s_wi[w] < ci)) { cv = s_wv[w]; ci = s_wi[w]; }
        }
        bmaxv[(size_t)b*NBX + blockIdx.x] = cv;
        bmaxi[(size_t)b*NBX + blockIdx.x] = ci;
    }

    // deferred repr finalize for the PREVIOUS iteration
    if (iter > 0 && blockIdx.x == 0) {
        const int slotPrev = (iter-1) & 1;
        double ss = sumSim[(size_t)slotPrev*BB + b];
        if (t < CC) {
            double c0 = 0.0, c1 = 0.0, c2 = 0.0, c3 = 0.0;
            for (int nb = 0; nb < NBX; nb += 4) {
                c0 += wpart[((size_t)(nb+0)*BB + b)*CC + t];
                c1 += wpart[((size_t)(nb+1)*BB + b)*CC + t];
                c2 += wpart[((size_t)(nb+2)*BB + b)*CC + t];
                c3 += wpart[((size_t)(nb+3)*BB + b)*CC + t];
            }
            double tot2 = ((c0 + c1) + (c2 + c3));
            out[(size_t)(iter-1)*BB*CC + (size_t)b*CC + t] = (float)(tot2 / ss);
        }
        __syncthreads();
        if (t == 0) sumSim[(size_t)slotPrev*BB + b] = 0.0;
    }

    // ---- last block per b: produce sel/rv/selpos for iter+1 ----
    if (iter < NBVEC-1) {
        if (t == 0) {
            __threadfence();                              // publish bmax partial
            int old = atomicAdd(&ticket[iter*BB + b], 1);
            s_last = (old == NBX-1) ? 1 : 0;
        }
        __syncthreads();
        if (s_last) {
            __threadfence();                              // acquire all partials
            if (t < NBX) { s_val[t] = bmaxv[(size_t)b*NBX + t];
                           s_idx[t] = bmaxi[(size_t)b*NBX + t]; }
            __syncthreads();
            for (int s = NBX/2; s > 0; s >>= 1) {
                if (t < s) {
                    double v2 = s_val[t+s]; int i2 = s_idx[t+s];
                    if (v2 > s_val[t] || (v2 == s_val[t] && i2 < s_idx[t])) {
                        s_val[t] = v2; s_idx[t] = i2;
                    }
                }
                __syncthreads();
            }
            const int sel = s_idx[0];
            rv[(size_t)b*CC + t] = x[((size_t)b*CC + t)*NN + sel];
            if (t == 0) out_selpos[(size_t)b*NN + sel] += 1.0f;
        }
    }
}

// One-shot init for iter 0: sel = N/2.
__global__ void init_rv_kernel(const float* __restrict__ x,
                               float* __restrict__ out,
                               float* __restrict__ rv)
{
    const int b = blockIdx.x;
    const int t = threadIdx.x;
    rv[(size_t)b*CC + t] = x[((size_t)b*CC + t)*NN + NN/2];
    if (t == 0) {
        float* out_selpos = out + (size_t)NBVEC*BB*CC + (size_t)NBVEC*BB*NN;
        out_selpos[(size_t)b*NN + NN/2] += 1.0f;
    }
}

// Final repr (iter 15): wpart from the tail fused call, sumSim slot 15&1.
__global__ void final_repr_kernel(float* __restrict__ out,
                                  const double* __restrict__ sumSim,
                                  const double* __restrict__ wpart)
{
    const int b = blockIdx.x;
    const int t = threadIdx.x;
    double ss = sumSim[(size_t)((NBVEC-1) & 1)*BB + b];
    if (t < CC) {
        double c0 = 0.0, c1 = 0.0, c2 = 0.0, c3 = 0.0;
        for (int nb = 0; nb < NBX; nb += 4) {
            c0 += wpart[((size_t)(nb+0)*BB + b)*CC + t];
            c1 += wpart[((size_t)(nb+1)*BB + b)*CC + t];
            c2 += wpart[((size_t)(nb+2)*BB + b)*CC + t];
            c3 += wpart[((size_t)(nb+3)*BB + b)*CC + t];
        }
        double tot = ((c0 + c1) + (c2 + c3));
        out[(size_t)(NBVEC-1)*BB*CC + (size_t)b*CC + t] = (float)(tot / ss);
    }
}

extern "C" void kernel_launch(void* const* d_in, const int* in_sizes, int n_in,
                              void* d_out, int out_size, void* d_ws, size_t ws_size,
                              hipStream_t stream)
{
    const float* x = (const float*)d_in[0];
    // d_in[1] (prior) is provably unused: ind at i==0 is forced to N/2 and
    // score is overwritten with (1 - sim) at i==0, discarding the prior.
    // d_in[2] (nbVec) fixed at 16 by the problem shapes.
    float* out = (float*)d_out;

    char* ws = (char*)d_ws;
    double* score  = (double*)(ws);
    float*  d2part = (float*) (ws + 1048576);
    double* wpart  = (double*)(ws + 9437184);
    double* sumSim = (double*)(ws + 10485760);
    double* bmaxv  = (double*)(ws + 10485888);
    int*    bmaxi  = (int*)   (ws + 10489984);
    float*  rv     = (float*) (ws + 10492032);
    int*    ticket = (int*)   (ws + 10500224);

    // d_out/d_ws are poisoned before every launch: zero what we accumulate into.
    float* out_selpos = out + (size_t)NBVEC*BB*CC + (size_t)NBVEC*BB*NN;
    hipMemsetAsync(out_selpos, 0, (size_t)BB*NN*sizeof(float), stream);
    hipMemsetAsync(sumSim, 0, 2*BB*sizeof(double), stream);
    hipMemsetAsync(ticket, 0, NBVEC*BB*sizeof(int), stream);

    init_rv_kernel<<<BB, 256, 0, stream>>>(x, out, rv);

    for (int i = 0; i <= NBVEC; ++i) {
        // F(i): d2 for rv_i (skipped at i==16), wsum for sim_{i-1} (skipped at i==0)
        fused_kernel<<<dim3(NBX, CSPLIT, BB), 256, 0, stream>>>(
            x, out, rv, d2part, wpart, i);
        if (i < NBVEC)
            finish_kernel<<<dim3(NBX, BB), 256, 0, stream>>>(
                x, out, score, d2part, sumSim, wpart, bmaxv, bmaxi, rv, ticket, i);
    }
    final_repr_kernel<<<BB, 256, 0, stream>>>(out, sumSim, wpart);
}

// Round 6
// 840.901 us; speedup vs baseline: 1.1964x; 1.1964x over previous
//
#include <hip/hip_runtime.h>
#include <math.h>

#define BB 8
#define CC 256
#define HH 128
#define WW 128
#define NN (HH*WW)          // 16384
#define NBVEC 16
#define CSPLIT 16
#define CCHUNK (CC/CSPLIT)  // 16
#define NBX (NN/256)        // 64  (finish blocks / wpart rows / bmax partials)
#define NBB 16              // fused nb blocks
#define NSUB 4              // sub-tiles per fused block (NBB*NSUB*256 == NN)

// ---------------- workspace layout (bytes) ----------------
// score  double[B][N]           @ 0        : 1048576
// d2part float [CSPLIT][B][N]   @ 1048576  : 8388608
// wpart  double[NBX][B][C]      @ 9437184  : 1048576
// sumSim double[2][B]           @ 10485760 : 128
// bmaxv  double[B][NBX]         @ 10485888 : 4096
// bmaxi  int   [B][NBX]         @ 10489984 : 2048
// total ~10.5 MB

// Fused kernel: ONE x-pass per iteration, software-pipelined.
// Grid (16,16,8) = 2048 blocks = 8/CU (one residency round). Block
// (nb,cz,b) owns c in [cz*16,cz*16+16) and FOUR 256-n sub-tiles
// n in [nb*1024, nb*1024+1024). Round-5 ticket/fence and float4-LDS
// staging reverted (both regressed); round-4 prologue restored, now
// amortized over 4 sub-tiles. Pipeline per sub-tile: write LDS tile,
// barrier, ISSUE next tile's 16 loads, then pass A + pass B while they
// fly (~600 cy compute covers L3 latency) -> continuous streaming
// instead of load-burst/compute-silence convoys (round-4..5 were
// latency-bound at ~3 TB/s effective with VALU ~6%).
__global__ __launch_bounds__(256, 8)
void fused_kernel(const float* __restrict__ x,
                  float* __restrict__ out,
                  const double* __restrict__ bmaxv,
                  const int* __restrict__ bmaxi,
                  float* __restrict__ d2part,
                  double* __restrict__ wpart, int iter)
{
    const int b  = blockIdx.z;
    const int cz = blockIdx.y;
    const int nb = blockIdx.x;     // 0..15
    const int t  = threadIdx.x;

    __shared__ float s_x[CCHUNK][257];   // 257-stride: all accesses <=2-way (free)
    __shared__ float s_sim[256];
    __shared__ float s_rv[CCHUNK];
    __shared__ union UScratch {
        double part[16][CCHUNK];                       // pass-B partials
        struct { double val[NBX]; int idx[NBX]; } mx;  // argmax reduce
    } s_u;

    float* out_sims   = out + (size_t)NBVEC*BB*CC;            // [NBVEC][B][N]
    float* out_selpos = out_sims + (size_t)NBVEC*BB*NN;       // [B][N]

    // ---- issue sub-tile 0 loads FIRST (fly under the prologue) ----
    const float* xb   = x + ((size_t)b*CC + (size_t)cz*CCHUNK)*NN + (size_t)nb*(NSUB*256);
    const float* simb = out_sims + (size_t)(iter-1)*BB*NN + (size_t)b*NN + (size_t)nb*(NSUB*256);
    float r[CCHUNK];
    #pragma unroll
    for (int c = 0; c < CCHUNK; ++c)
        r[c] = xb[(size_t)c*NN + t];
    float simreg = 0.0f;
    if (iter > 0) simreg = simb[t];

    // ---- select index (redundant per block; first-occurrence tie-break) ----
    int sel = NN/2;
    if (iter > 0 && iter < NBVEC) {
        if (t < NBX) { s_u.mx.val[t] = bmaxv[b*NBX + t]; s_u.mx.idx[t] = bmaxi[b*NBX + t]; }
        __syncthreads();
        for (int s = NBX/2; s > 0; s >>= 1) {
            if (t < s) {
                double v2 = s_u.mx.val[t+s]; int i2 = s_u.mx.idx[t+s];
                if (v2 > s_u.mx.val[t] || (v2 == s_u.mx.val[t] && i2 < s_u.mx.idx[t])) {
                    s_u.mx.val[t] = v2; s_u.mx.idx[t] = i2;
                }
            }
            __syncthreads();
        }
        sel = s_u.mx.idx[0];   // into register before union is reused
    }

    if (iter < NBVEC) {
        if (t < CCHUNK)
            s_rv[t] = x[((size_t)b*CC + (size_t)cz*CCHUNK + t)*NN + sel];
        if (t == 0 && nb == 0 && cz == 0)
            out_selpos[(size_t)b*NN + sel] += 1.0f;
    }

    // ---- 4 sub-tiles, software-pipelined ----
    for (int sub = 0; sub < NSUB; ++sub) {
        __syncthreads();               // prior s_x/s_u fully consumed
        #pragma unroll
        for (int c = 0; c < CCHUNK; ++c)
            s_x[c][t] = r[c];
        if (iter > 0) s_sim[t] = simreg;
        __syncthreads();               // tile ready

        if (sub + 1 < NSUB) {          // prefetch next tile NOW; compute hides it
            const int off = (sub+1)*256;
            #pragma unroll
            for (int c = 0; c < CCHUNK; ++c)
                r[c] = xb[(size_t)c*NN + off + t];
            if (iter > 0) simreg = simb[off + t];
        }

        const int n = nb*(NSUB*256) + sub*256 + t;

        // pass A: d2 partial (fp64 chain, fixed c-ascending order; values
        // bit-identical to round 4: s_x holds exactly r's bits)
        if (iter < NBVEC) {
            double acc = 0.0;
            #pragma unroll
            for (int c = 0; c < CCHUNK; ++c) {
                double diff = (double)s_x[c][t] - (double)s_rv[c];
                acc = fma(diff, diff, acc);
            }
            d2part[((size_t)cz*BB + b)*NN + n] = (float)acc;
        }

        // pass B: wsum partial for previous iter's sim
        if (iter > 0) {
            const int c = t & 15;      // 16 c's
            const int g = t >> 4;      // 16 n-groups of 16
            double w = 0.0;
            #pragma unroll
            for (int k = 0; k < 16; ++k) {
                const int nn2 = g*16 + k;
                w = fma((double)s_sim[nn2], (double)s_x[c][nn2], w);
            }
            s_u.part[g][c] = w;
            __syncthreads();
            if (t < CCHUNK) {
                double t0 = 0.0, t1 = 0.0;
                #pragma unroll
                for (int gg = 0; gg < 16; gg += 2) {   // fixed order, 2 chains
                    t0 += s_u.part[gg][t];
                    t1 += s_u.part[gg+1][t];
                }
                const int nbg = nb*NSUB + sub;         // same 256-n grouping as round 4
                wpart[((size_t)nbg*BB + b)*CC + (size_t)cz*CCHUNK + t] = t0 + t1;
            }
        }
    }
}

// Finisher: grid (N/256, B) — verbatim round 4 (no ticket, no fence).
//  - d2 = sum of 16 fp32 partials; sim = exp(-sqrt(d2+1e-12)/20)
//  - out_sims (fp32), score update (fp64)
//  - sumSim + argmax via per-wave shfl butterflies (semilattice: order-free)
//  - block (0,b), iter>0: repr_{iter-1} finalize
__global__ void finish_kernel(float* __restrict__ out,
                              double* __restrict__ score,
                              const float* __restrict__ d2part,
                              double* __restrict__ sumSim,
                              const double* __restrict__ wpart,
                              double* __restrict__ bmaxv,
                              int* __restrict__ bmaxi, int iter)
{
    const int b = blockIdx.y;
    const int t = threadIdx.x;
    const int n = blockIdx.x * 256 + t;
    const size_t si = (size_t)b*NN + n;
    const int lane = t & 63;
    const int wave = t >> 6;

    double a0 = 0.0, a1 = 0.0;
    #pragma unroll
    for (int cz = 0; cz < CSPLIT; cz += 2) {
        a0 += (double)d2part[((size_t)cz*BB + b)*NN + n];
        a1 += (double)d2part[((size_t)(cz+1)*BB + b)*NN + n];
    }
    double d2 = a0 + a1;

    double d   = sqrt(d2 + 1e-12);
    double sim = exp(-(d / 20.0));

    float* out_sims = out + (size_t)NBVEC*BB*CC;   // [NBVEC][B][N]
    out_sims[(size_t)iter*BB*NN + si] = (float)sim;

    double sc;
    if (iter == 0) sc = 1.0 - sim;
    else           sc = (1.0 - sim) * score[si];
    score[si] = sc;

    // per-wave sumSim reduce (butterfly, fixed order)
    double v = sim;
    #pragma unroll
    for (int off = 32; off > 0; off >>= 1) v += __shfl_down(v, off, 64);

    // per-wave argmax reduce (max, lower-idx-on-tie: semilattice)
    double bv = sc; int bi = n;
    #pragma unroll
    for (int off = 32; off > 0; off >>= 1) {
        double ov = __shfl_down(bv, off, 64);
        int    oi = __shfl_down(bi, off, 64);
        if (ov > bv || (ov == bv && oi < bi)) { bv = ov; bi = oi; }
    }

    __shared__ double s_ws[4];
    __shared__ double s_wv[4];
    __shared__ int    s_wi[4];
    if (lane == 0) { s_ws[wave] = v; s_wv[wave] = bv; s_wi[wave] = bi; }
    __syncthreads();
    if (t == 0) {
        double tot = ((s_ws[0] + s_ws[1]) + (s_ws[2] + s_ws[3]));  // fixed order
        atomicAdd(&sumSim[(size_t)(iter & 1)*BB + b], tot);
        double cv = s_wv[0]; int ci = s_wi[0];
        #pragma unroll
        for (int w = 1; w < 4; ++w) {        // ascending wave = ascending n
            if (s_wv[w] > cv || (s_wv[w] == cv && s_wi[w] < ci)) { cv = s_wv[w]; ci = s_wi[w]; }
        }
        bmaxv[(size_t)b*NBX + blockIdx.x] = cv;
        bmaxi[(size_t)b*NBX + blockIdx.x] = ci;
    }

    // deferred repr finalize for the PREVIOUS iteration (4 fixed-order chains)
    if (iter > 0 && blockIdx.x == 0) {
        const int slotPrev = (iter-1) & 1;
        double ss = sumSim[(size_t)slotPrev*BB + b];
        if (t < CC) {
            double c0 = 0.0, c1 = 0.0, c2 = 0.0, c3 = 0.0;
            for (int nb = 0; nb < NBX; nb += 4) {
                c0 += wpart[((size_t)(nb+0)*BB + b)*CC + t];
                c1 += wpart[((size_t)(nb+1)*BB + b)*CC + t];
                c2 += wpart[((size_t)(nb+2)*BB + b)*CC + t];
                c3 += wpart[((size_t)(nb+3)*BB + b)*CC + t];
            }
            double tot2 = ((c0 + c1) + (c2 + c3));
            out[(size_t)(iter-1)*BB*CC + (size_t)b*CC + t] = (float)(tot2 / ss);
        }
        __syncthreads();
        if (t == 0) sumSim[(size_t)slotPrev*BB + b] = 0.0;
    }
}

// Final repr (iter 15): wpart from the tail fused call, sumSim slot 15&1.
__global__ void final_repr_kernel(float* __restrict__ out,
                                  const double* __restrict__ sumSim,
                                  const double* __restrict__ wpart)
{
    const int b = blockIdx.x;
    const int t = threadIdx.x;
    double ss = sumSim[(size_t)((NBVEC-1) & 1)*BB + b];
    if (t < CC) {
        double c0 = 0.0, c1 = 0.0, c2 = 0.0, c3 = 0.0;
        for (int nb = 0; nb < NBX; nb += 4) {
            c0 += wpart[((size_t)(nb+0)*BB + b)*CC + t];
            c1 += wpart[((size_t)(nb+1)*BB + b)*CC + t];
            c2 += wpart[((size_t)(nb+2)*BB + b)*CC + t];
            c3 += wpart[((size_t)(nb+3)*BB + b)*CC + t];
        }
        double tot = ((c0 + c1) + (c2 + c3));
        out[(size_t)(NBVEC-1)*BB*CC + (size_t)b*CC + t] = (float)(tot / ss);
    }
}

extern "C" void kernel_launch(void* const* d_in, const int* in_sizes, int n_in,
                              void* d_out, int out_size, void* d_ws, size_t ws_size,
                              hipStream_t stream)
{
    const float* x = (const float*)d_in[0];
    // d_in[1] (prior) is provably unused: ind at i==0 is forced to N/2 and
    // score is overwritten with (1 - sim) at i==0, discarding the prior.
    // d_in[2] (nbVec) fixed at 16 by the problem shapes.
    float* out = (float*)d_out;

    char* ws = (char*)d_ws;
    double* score  = (double*)(ws);
    float*  d2part = (float*) (ws + 1048576);
    double* wpart  = (double*)(ws + 9437184);
    double* sumSim = (double*)(ws + 10485760);
    double* bmaxv  = (double*)(ws + 10485888);
    int*    bmaxi  = (int*)   (ws + 10489984);

    // d_out/d_ws are poisoned before every launch: zero what we accumulate into.
    float* out_selpos = out + (size_t)NBVEC*BB*CC + (size_t)NBVEC*BB*NN;
    hipMemsetAsync(out_selpos, 0, (size_t)BB*NN*sizeof(float), stream);
    hipMemsetAsync(sumSim, 0, 2*BB*sizeof(double), stream);

    for (int i = 0; i <= NBVEC; ++i) {
        // F(i): d2 for rv_i (skipped at i==16), wsum for sim_{i-1} (skipped at i==0)
        fused_kernel<<<dim3(NBB, CSPLIT, BB), 256, 0, stream>>>(
            x, out, bmaxv, bmaxi, d2part, wpart, i);
        if (i < NBVEC)
            finish_kernel<<<dim3(NBX, BB), 256, 0, stream>>>(
                out, score, d2part, sumSim, wpart, bmaxv, bmaxi, i);
    }
    final_repr_kernel<<<BB, 256, 0, stream>>>(out, sumSim, wpart);
}